// Round 11
// baseline (1188.210 us; speedup 1.0000x reference)
//
#include <hip/hip_runtime.h>
#include <stdint.h>

// Problem constants
#define N_ROWS 32768
#define KCODES 8192
#define DIM    512
#define DECAYF 0.8f
#define EPSF   1e-5f

// d_out layout (float32, reference return order)
#define OUT_QUANT 0
#define OUT_IND   (N_ROWS * DIM)                 // 16777216
#define OUT_CSN   (OUT_IND + N_ROWS)             // 16809984
#define OUT_AVG   (OUT_CSN + KCODES)             // 16818176
#define OUT_NORM  (OUT_AVG + KCODES * DIM)       // 21012480

// During dist_k the quant region (64 MiB) holds the X f16 planes (Xh 32 MiB + Xm 32 MiB);
// overwritten by assign_k afterwards.
// ws: [0,256K) best u64; [256K,288K) norm2; [288K] S; [+4] inv_cs; [1MiB..) Eh, Em (8 MiB each).

typedef _Float16 f16x8 __attribute__((ext_vector_type(8)));
typedef __attribute__((ext_vector_type(4))) float f32x4;

__device__ __forceinline__ unsigned int enc_f(float v) {
    unsigned int b = __float_as_uint(v);
    return (b & 0x80000000u) ? ~b : (b | 0x80000000u);
}

__device__ __forceinline__ void gl16(const _Float16* g, const char* lds) {
    __builtin_amdgcn_global_load_lds(
        (const __attribute__((address_space(1))) unsigned int*)g,
        (__attribute__((address_space(3))) unsigned int*)lds, 16, 0, 0);
}

// ---- split fp32 -> f16 planes: h = f16(v), m' = f16((v-h)*1024); + best-init ----
__global__ void cvt_x_k(const float* __restrict__ src, _Float16* __restrict__ ph,
                        _Float16* __restrict__ pm, unsigned long long* __restrict__ best) {
    int i = blockIdx.x * 256 + threadIdx.x;      // < N_ROWS*DIM/8
    if (i < N_ROWS) best[i] = 0ull;
    const float4* s4 = (const float4*)src;
    float4 v0 = s4[(size_t)i * 2], v1 = s4[(size_t)i * 2 + 1];
    float f[8] = {v0.x, v0.y, v0.z, v0.w, v1.x, v1.y, v1.z, v1.w};
    f16x8 hv, mv;
    #pragma unroll
    for (int j = 0; j < 8; ++j) {
        _Float16 h = (_Float16)f[j];
        float r = f[j] - (float)h;
        hv[j] = h;
        mv[j] = (_Float16)(r * 1024.0f);
    }
    *(f16x8*)(ph + (size_t)i * 8) = hv;
    *(f16x8*)(pm + (size_t)i * 8) = mv;
}

// ---- embed split + fused per-code squared norm (64 threads == 1 code row) ----
__global__ void cvt_e_k(const float* __restrict__ src, _Float16* __restrict__ ph,
                        _Float16* __restrict__ pm, float* __restrict__ norm2) {
    int i = blockIdx.x * 256 + threadIdx.x;      // < KCODES*DIM/8
    const float4* s4 = (const float4*)src;
    float4 v0 = s4[(size_t)i * 2], v1 = s4[(size_t)i * 2 + 1];
    float f[8] = {v0.x, v0.y, v0.z, v0.w, v1.x, v1.y, v1.z, v1.w};
    f16x8 hv, mv;
    float s = 0.f;
    #pragma unroll
    for (int j = 0; j < 8; ++j) {
        _Float16 h = (_Float16)f[j];
        float r = f[j] - (float)h;
        hv[j] = h;
        mv[j] = (_Float16)(r * 1024.0f);
        s += f[j] * f[j];
    }
    *(f16x8*)(ph + (size_t)i * 8) = hv;
    *(f16x8*)(pm + (size_t)i * 8) = mv;
    #pragma unroll
    for (int off = 32; off; off >>= 1) s += __shfl_down(s, off);
    if ((threadIdx.x & 63) == 0) norm2[i >> 6] = s;   // row = i*8/512
}

// ---- K1: 256x256 tile, 8 waves, 3-phase/chunk schedule, counted-vmcnt dbuf ----
#define BM 256
#define BN 256
#define BK 32
#define PTILE 16384     // bytes per plane tile: 256 rows x 32 f16
#define LBUF  65536     // one LDS buffer: 4 planes (Ah Am Bh Bm)

__global__ __launch_bounds__(512, 2) void dist_k(
    const _Float16* __restrict__ Xh, const _Float16* __restrict__ Xm,
    const _Float16* __restrict__ Eh, const _Float16* __restrict__ Em,
    const float* __restrict__ norm2, unsigned long long* __restrict__ best)
{
    extern __shared__ char sb[];   // 128 KiB: 2 x (Ah Am Bh Bm)

    const int tid = threadIdx.x;
    const int w = tid >> 6, l = tid & 63;

    // XCD column-band mapping: 4096 blocks; XCD (b&7) owns 4 consecutive bx; bx-minor.
    int b = blockIdx.x;
    int xcd = b & 7;
    int local = b >> 3;            // 0..511
    int bxl = local & 3;
    int by = local >> 2;           // 0..127
    int bx = xcd * 4 + bxl;        // 0..31
    const int rBase = by * BM, cBase = bx * BN;

    // staging: per plane 2 rounds of 8 KiB (512 thr x 16 B); pre-swizzled source col
    int o0 = tid << 4;             // 0..8191
    int row0 = o0 >> 6;            // 0..127 (round2: +128)
    int c0 = (((o0 >> 4) & 3) ^ ((row0 >> 1) & 3)) << 3;
    unsigned offA0 = (unsigned)(rBase + row0) * DIM + c0;
    unsigned offA1 = offA0 + 128 * DIM;
    unsigned offB0 = (unsigned)(cBase + row0) * DIM + c0;
    unsigned offB1 = offB0 + 128 * DIM;

    const int wr = w >> 2, wc = w & 3;     // 2x4 wave grid, 128x64 output each
    const int ln = l & 15, kq = l >> 4;

    // fragment read bases (proven conflict-free; swizzle invariant across ai/bj)
    const int swz = ((kq ^ ((ln >> 1) & 3)) << 4);
    const int baA = (wr * 128 + ln) * 64 + swz;    // + ai*1024, ai 0..7
    const int baB = (wc * 64 + ln) * 64 + swz;     // + bj*1024, bj 0..3

    f32x4 acc[8][4];
    #pragma unroll
    for (int i = 0; i < 8; ++i)
        #pragma unroll
        for (int j = 0; j < 4; ++j) acc[i][j] = (f32x4){0.f, 0.f, 0.f, 0.f};

    const _Float16 SC = (_Float16)0.0009765625f;   // 2^-10 exact

    f16x8 ah[8], bh[4], bm[4];

    // staging pieces in fixed issue order: p1=[XhA0,XhA1,EhB0] p2=[EhB1,EmB0,EmB1] p3=[XmA0,XmA1]
    #define STG1(Y, DN) { \
        gl16(Xh + offA0 + (DN), sb + (Y) + 0 * PTILE + o0); \
        gl16(Xh + offA1 + (DN), sb + (Y) + 0 * PTILE + 8192 + o0); \
        gl16(Eh + offB0 + (DN), sb + (Y) + 2 * PTILE + o0); \
    }
    #define STG2(Y, DN) { \
        gl16(Eh + offB1 + (DN), sb + (Y) + 2 * PTILE + 8192 + o0); \
        gl16(Em + offB0 + (DN), sb + (Y) + 3 * PTILE + o0); \
        gl16(Em + offB1 + (DN), sb + (Y) + 3 * PTILE + 8192 + o0); \
    }
    #define STG3(Y, DN) { \
        gl16(Xm + offA0 + (DN), sb + (Y) + 1 * PTILE + o0); \
        gl16(Xm + offA1 + (DN), sb + (Y) + 1 * PTILE + 8192 + o0); \
    }

    #define MFMA32(AV, BV) { \
        _Pragma("unroll") \
        for (int bj = 0; bj < 4; ++bj) \
            _Pragma("unroll") \
            for (int ai = 0; ai < 8; ++ai) \
                acc[ai][bj] = __builtin_amdgcn_mfma_f32_16x16x32_f16(AV[ai], BV[bj], acc[ai][bj], 0, 0, 0); \
    }

    #define PHASE_TAIL(VM) { \
        asm volatile("s_waitcnt vmcnt(" #VM ")" ::: "memory"); \
        __builtin_amdgcn_s_barrier(); \
        asm volatile("s_waitcnt lgkmcnt(0)" ::: "memory"); \
        __builtin_amdgcn_sched_barrier(0); \
    }
    #define PHASE_TAIL_NOVM() { \
        __builtin_amdgcn_s_barrier(); \
        asm volatile("s_waitcnt lgkmcnt(0)" ::: "memory"); \
        __builtin_amdgcn_sched_barrier(0); \
    }

    // prologue: stage chunk 0 into buf0 in canonical order, guarantee first-4 done
    STG1(0, 0) STG2(0, 0) STG3(0, 0)
    asm volatile("s_waitcnt vmcnt(4)" ::: "memory");
    __builtin_amdgcn_s_barrier();

    #pragma unroll
    for (int t = 0; t < 16; ++t) {
        const int X = (t & 1) ? LBUF : 0;
        const int Y = X ^ LBUF;
        const int dn = t * 32 + 32;

        // ---- phase 1: ah, bh ; stage p1 of t+1 ; wait covers p2 reads (Em of t) ----
        #pragma unroll
        for (int ai = 0; ai < 8; ++ai)
            ah[ai] = *(const f16x8*)(sb + X + 0 * PTILE + baA + ai * 1024);
        #pragma unroll
        for (int bj = 0; bj < 4; ++bj)
            bh[bj] = *(const f16x8*)(sb + X + 2 * PTILE + baB + bj * 1024);
        if (t < 15) { STG1(Y, dn) PHASE_TAIL(5) } else { PHASE_TAIL(2) }
        __builtin_amdgcn_s_setprio(1);
        MFMA32(ah, bh)
        __builtin_amdgcn_s_setprio(0);
        __builtin_amdgcn_s_barrier();

        // ---- phase 2: bm ; ah *= 2^-10 ; stage p2 ; wait covers p3 reads (Xm of t) ----
        #pragma unroll
        for (int bj = 0; bj < 4; ++bj)
            bm[bj] = *(const f16x8*)(sb + X + 3 * PTILE + baB + bj * 1024);
        #pragma unroll
        for (int ai = 0; ai < 8; ++ai) ah[ai] *= SC;
        if (t < 15) { STG2(Y, dn) PHASE_TAIL(6) } else { PHASE_TAIL(0) }
        __builtin_amdgcn_s_setprio(1);
        MFMA32(ah, bm)
        __builtin_amdgcn_s_setprio(0);
        __builtin_amdgcn_s_barrier();

        // ---- phase 3: am (reuse ah regs) ; bh *= 2^-10 ; stage p3 ; wait covers next p1 ----
        #pragma unroll
        for (int ai = 0; ai < 8; ++ai)
            ah[ai] = *(const f16x8*)(sb + X + 1 * PTILE + baA + ai * 1024);
        #pragma unroll
        for (int bj = 0; bj < 4; ++bj) bh[bj] *= SC;
        if (t < 15) { STG3(Y, dn) PHASE_TAIL(4) } else { PHASE_TAIL_NOVM() }
        __builtin_amdgcn_s_setprio(1);
        MFMA32(ah, bh)
        __builtin_amdgcn_s_setprio(0);
        __builtin_amdgcn_s_barrier();
    }
    #undef STG1
    #undef STG2
    #undef STG3
    #undef MFMA32
    #undef PHASE_TAIL
    #undef PHASE_TAIL_NOVM

    // ---- epilogue: dist = 2*acc - ||e||^2 ; per-row argmax via packed atomicMax ----
    float n2v[4];
    #pragma unroll
    for (int bj = 0; bj < 4; ++bj)
        n2v[bj] = norm2[cBase + wc * 64 + bj * 16 + ln];

    #pragma unroll
    for (int ai = 0; ai < 8; ++ai) {
        #pragma unroll
        for (int r = 0; r < 4; ++r) {
            float bval = -3.4e38f;
            int bidx = 0;
            #pragma unroll
            for (int bj = 0; bj < 4; ++bj) {
                float v = 2.f * acc[ai][bj][r] - n2v[bj];
                if (v > bval) { bval = v; bidx = cBase + wc * 64 + bj * 16 + ln; }
            }
            #pragma unroll
            for (int off = 1; off < 16; off <<= 1) {
                float ov = __shfl_xor(bval, off);
                int   oi = __shfl_xor(bidx, off);
                if (ov > bval || (ov == bval && oi < bidx)) { bval = ov; bidx = oi; }
            }
            if (ln == 0) {
                unsigned long long key =
                    ((unsigned long long)enc_f(bval) << 32) | (unsigned int)(~(unsigned int)bidx);
                atomicMax(&best[rBase + wr * 128 + ai * 16 + kq * 4 + r], key);
            }
        }
    }
}

// ---- post-dist init: csn = 0.8*cs ; avg = 0.8*eavg ----
__global__ void init2_k(const float* __restrict__ cs, const float* __restrict__ eavg,
                        float* __restrict__ out) {
    int i = blockIdx.x * blockDim.x + threadIdx.x;
    int stride = gridDim.x * blockDim.x;
    for (int idx = i; idx < KCODES * DIM; idx += stride) {
        out[OUT_AVG + idx] = DECAYF * eavg[idx];
        if (idx < KCODES) out[OUT_CSN + idx] = DECAYF * cs[idx];
    }
}

// ---- gather quantize + scatter counts/embed_sum ----
__global__ void assign_k(const float* __restrict__ x, const float* __restrict__ embed,
                         const unsigned long long* __restrict__ best, float* __restrict__ out) {
    int row = blockIdx.x, lane = threadIdx.x;
    int idx = (int)(~(unsigned int)best[row]);
    if (lane == 0) {
        out[OUT_IND + row] = (float)idx;
        atomicAdd(&out[OUT_CSN + idx], 0.2f);
    }
    const float4* e  = (const float4*)(embed + (size_t)idx * DIM);
    const float4* xr = (const float4*)(x + (size_t)row * DIM);
    float4* q = (float4*)(out + OUT_QUANT + (size_t)row * DIM);
    float* avg = out + OUT_AVG + (size_t)idx * DIM;
    #pragma unroll
    for (int j = lane; j < DIM / 4; j += 64) {
        q[j] = e[j];
        float4 xv = xr[j];
        atomicAdd(&avg[j * 4 + 0], 0.2f * xv.x);
        atomicAdd(&avg[j * 4 + 1], 0.2f * xv.y);
        atomicAdd(&avg[j * 4 + 2], 0.2f * xv.z);
        atomicAdd(&avg[j * 4 + 3], 0.2f * xv.w);
    }
}

// ---- fused: S = sum(csn) then inv_cs[k] ----
__global__ void sumInv_k(const float* __restrict__ out, float* __restrict__ Sout,
                         float* __restrict__ inv_cs) {
    __shared__ float red[4];
    float s = 0.f;
    for (int i = threadIdx.x; i < KCODES; i += 256) s += out[OUT_CSN + i];
    #pragma unroll
    for (int off = 32; off; off >>= 1) s += __shfl_down(s, off);
    if ((threadIdx.x & 63) == 0) red[threadIdx.x >> 6] = s;
    __syncthreads();
    float Sv = red[0] + red[1] + red[2] + red[3];
    if (threadIdx.x == 0) Sout[0] = Sv;
    for (int k = threadIdx.x; k < KCODES; k += 256)
        inv_cs[k] = (Sv + (float)KCODES * EPSF) / ((out[OUT_CSN + k] + EPSF) * Sv);
}

__global__ void normout_k(float* __restrict__ out, const float* __restrict__ inv_cs) {
    int i = blockIdx.x * 256 + threadIdx.x;
    const float4* avg = (const float4*)(out + OUT_AVG);
    float4* nrm = (float4*)(out + OUT_NORM);
    float inv = inv_cs[i >> 7];
    float4 v = avg[i];
    v.x *= inv; v.y *= inv; v.z *= inv; v.w *= inv;
    nrm[i] = v;
}

extern "C" void kernel_launch(void* const* d_in, const int* in_sizes, int n_in,
                              void* d_out, int out_size, void* d_ws, size_t ws_size,
                              hipStream_t stream) {
    const float* x     = (const float*)d_in[0];
    const float* embed = (const float*)d_in[1];
    const float* cs    = (const float*)d_in[2];
    const float* eavg  = (const float*)d_in[3];
    float* out = (float*)d_out;
    char*  w   = (char*)d_ws;

    unsigned long long* best = (unsigned long long*)w;
    float* norm2  = (float*)(w + 262144);
    float* Ssum   = (float*)(w + 294912);
    float* inv_cs = Ssum + 1;
    _Float16* Eh = (_Float16*)(w + (1u << 20));
    _Float16* Em = Eh + (size_t)KCODES * DIM;

    // X planes exactly fill the quant region (64 MiB), rewritten later by assign_k
    _Float16* Xh = (_Float16*)out;
    _Float16* Xm = Xh + (size_t)N_ROWS * DIM;

    // allow 128 KiB dynamic LDS for dist_k (host-side, graph-capture safe)
    hipFuncSetAttribute((const void*)dist_k,
                        hipFuncAttributeMaxDynamicSharedMemorySize, 131072);

    cvt_x_k<<<(N_ROWS * DIM / 8) / 256, 256, 0, stream>>>(x, Xh, Xm, best);
    cvt_e_k<<<(KCODES * DIM / 8) / 256, 256, 0, stream>>>(embed, Eh, Em, norm2);
    dist_k<<<(N_ROWS / BM) * (KCODES / BN), 512, 131072, stream>>>(Xh, Xm, Eh, Em, norm2, best);
    init2_k<<<2048, 256, 0, stream>>>(cs, eavg, out);
    assign_k<<<N_ROWS, 64, 0, stream>>>(x, embed, best, out);
    sumInv_k<<<1, 256, 0, stream>>>(out, Ssum, inv_cs);
    normout_k<<<(KCODES * DIM / 4) / 256, 256, 0, stream>>>(out, inv_cs);
}

// Round 12
// 926.695 us; speedup vs baseline: 1.2822x; 1.2822x over previous
//
#include <hip/hip_runtime.h>
#include <stdint.h>

// Problem constants
#define N_ROWS 32768
#define KCODES 8192
#define DIM    512
#define DECAYF 0.8f
#define EPSF   1e-5f
#define CAP    96      // rowlist slots per code (avg 4 rows/code; overflow -> atomic fallback)

// d_out layout (float32, reference return order)
#define OUT_QUANT 0
#define OUT_IND   (N_ROWS * DIM)                 // 16777216
#define OUT_CSN   (OUT_IND + N_ROWS)             // 16809984
#define OUT_AVG   (OUT_CSN + KCODES)             // 16818176
#define OUT_NORM  (OUT_AVG + KCODES * DIM)       // 21012480

// During dist_k the quant region (64 MiB) holds the X f16 planes (Xh 32 MiB + Xm 32 MiB);
// rewritten by quant_slot_k afterwards. avg/csn regions are initialized pre-dist (legal:
// dist touches only the quant region + ws).
// ws: [0,256K) best u64; [256K,288K) norm2; [288K] S; [+4,+32K) inv_cs;
//     [1MiB) Eh, Em (8 MiB each); [20MiB) cnt u32[8192]; [+32K) rowlist u32[8192*96] (3 MiB).

typedef _Float16 f16x8 __attribute__((ext_vector_type(8)));
typedef __attribute__((ext_vector_type(4))) float f32x4;

__device__ __forceinline__ unsigned int enc_f(float v) {
    unsigned int b = __float_as_uint(v);
    return (b & 0x80000000u) ? ~b : (b | 0x80000000u);
}

__device__ __forceinline__ void gl16(const _Float16* g, const char* lds) {
    __builtin_amdgcn_global_load_lds(
        (const __attribute__((address_space(1))) unsigned int*)g,
        (__attribute__((address_space(3))) unsigned int*)lds, 16, 0, 0);
}

// ---- X split + best/cnt init + csn/avg EMA-init (absorbs old init2) ----
__global__ void cvt_x_k(const float* __restrict__ src, _Float16* __restrict__ ph,
                        _Float16* __restrict__ pm, unsigned long long* __restrict__ best,
                        unsigned int* __restrict__ cnt, const float* __restrict__ cs,
                        const float* __restrict__ eavg, float* __restrict__ out) {
    int i = blockIdx.x * 256 + threadIdx.x;      // < N_ROWS*DIM/8 = 2097152
    if (i < N_ROWS) best[i] = 0ull;
    if (i < KCODES) { cnt[i] = 0u; out[OUT_CSN + i] = DECAYF * cs[i]; }
    if (i < KCODES * DIM / 4) {                  // avg = 0.8*eavg, float4-wide
        float4 v = ((const float4*)eavg)[i];
        v.x *= DECAYF; v.y *= DECAYF; v.z *= DECAYF; v.w *= DECAYF;
        ((float4*)(out + OUT_AVG))[i] = v;
    }
    const float4* s4 = (const float4*)src;
    float4 v0 = s4[(size_t)i * 2], v1 = s4[(size_t)i * 2 + 1];
    float f[8] = {v0.x, v0.y, v0.z, v0.w, v1.x, v1.y, v1.z, v1.w};
    f16x8 hv, mv;
    #pragma unroll
    for (int j = 0; j < 8; ++j) {
        _Float16 h = (_Float16)f[j];
        float r = f[j] - (float)h;
        hv[j] = h;
        mv[j] = (_Float16)(r * 1024.0f);
    }
    *(f16x8*)(ph + (size_t)i * 8) = hv;
    *(f16x8*)(pm + (size_t)i * 8) = mv;
}

// ---- embed split + fused per-code squared norm (64 threads == 1 code row) ----
__global__ void cvt_e_k(const float* __restrict__ src, _Float16* __restrict__ ph,
                        _Float16* __restrict__ pm, float* __restrict__ norm2) {
    int i = blockIdx.x * 256 + threadIdx.x;      // < KCODES*DIM/8
    const float4* s4 = (const float4*)src;
    float4 v0 = s4[(size_t)i * 2], v1 = s4[(size_t)i * 2 + 1];
    float f[8] = {v0.x, v0.y, v0.z, v0.w, v1.x, v1.y, v1.z, v1.w};
    f16x8 hv, mv;
    float s = 0.f;
    #pragma unroll
    for (int j = 0; j < 8; ++j) {
        _Float16 h = (_Float16)f[j];
        float r = f[j] - (float)h;
        hv[j] = h;
        mv[j] = (_Float16)(r * 1024.0f);
        s += f[j] * f[j];
    }
    *(f16x8*)(ph + (size_t)i * 8) = hv;
    *(f16x8*)(pm + (size_t)i * 8) = mv;
    #pragma unroll
    for (int off = 32; off; off >>= 1) s += __shfl_down(s, off);
    if ((threadIdx.x & 63) == 0) norm2[i >> 6] = s;   // row = i*8/512
}

// ---- K1: f16 3-pass dual-acc MFMA GEMM, counted-vmcnt 2-buffer pipeline (R6, 846us) ----
#define BM 128
#define BN 128
#define BK 32
#define TILEB 8192      // bytes per plane tile: 128 rows x 32 f16
#define LBUF  32768     // one LDS buffer: 4 planes (Ah Am Bh Bm)

__global__ __launch_bounds__(256, 2) void dist_k(
    const _Float16* __restrict__ Xh, const _Float16* __restrict__ Xm,
    const _Float16* __restrict__ Eh, const _Float16* __restrict__ Em,
    const float* __restrict__ norm2, unsigned long long* __restrict__ best)
{
    __shared__ _Float16 smem[2 * 4 * 4096];   // 64 KiB: 2 x (Ah Am Bh Bm)
    char* sb = (char*)smem;

    const int tid = threadIdx.x;
    const int w = tid >> 6, l = tid & 63;

    // XCD column-band mapping: XCD (b&7) owns 8 consecutive bx; bx-minor, by-major.
    int b = blockIdx.x;
    int xcd = b & 7;
    int local = b >> 3;
    int bxl = local & 7;
    int by = local >> 3;
    int bx = xcd * 8 + bxl;
    const int rBase = by * BM, cBase = bx * BN;

    // staging: 2 rounds/plane, linear LDS dest, pre-swizzled source (granule ^ (row>>1)&3)
    int o0 = (w << 10) | (l << 4);
    int o1 = o0 + 4096;
    int row0 = o0 >> 6, kb0 = (o0 >> 4) & 3;
    int row1 = o1 >> 6, kb1 = (o1 >> 4) & 3;
    int c0 = (kb0 ^ ((row0 >> 1) & 3)) << 3;
    int c1 = (kb1 ^ ((row1 >> 1) & 3)) << 3;
    unsigned offA0 = (unsigned)(rBase + row0) * DIM + c0;
    unsigned offA1 = (unsigned)(rBase + row1) * DIM + c1;
    unsigned offB0 = (unsigned)(cBase + row0) * DIM + c0;
    unsigned offB1 = (unsigned)(cBase + row1) * DIM + c1;
    const int w1024 = w << 10;

    const int wr = w >> 1, wc = w & 1;     // 2x2 wave grid, 64x64 output each
    const int ln = l & 15, kq = l >> 4;

    // ds_read bases (proven conflict-free 16x16 geometry from R3)
    const int rA = wr * 64 + ln;
    const int baA = rA * 64 + ((kq ^ ((rA >> 1) & 3)) << 4);
    const int rB = wc * 64 + ln;
    const int baB = rB * 64 + ((kq ^ ((rB >> 1) & 3)) << 4);

    f32x4 acc1[4][4], acc2[4][4];
    #pragma unroll
    for (int i = 0; i < 4; ++i)
        #pragma unroll
        for (int j = 0; j < 4; ++j) {
            acc1[i][j] = (f32x4){0.f, 0.f, 0.f, 0.f};
            acc2[i][j] = (f32x4){0.f, 0.f, 0.f, 0.f};
        }

    #define STAGE(BUFOFF, D0) { \
        gl16(Xh + offA0 + (D0), sb + (BUFOFF) + 0 * TILEB + w1024); \
        gl16(Xh + offA1 + (D0), sb + (BUFOFF) + 0 * TILEB + 4096 + w1024); \
        gl16(Xm + offA0 + (D0), sb + (BUFOFF) + 1 * TILEB + w1024); \
        gl16(Xm + offA1 + (D0), sb + (BUFOFF) + 1 * TILEB + 4096 + w1024); \
        gl16(Eh + offB0 + (D0), sb + (BUFOFF) + 2 * TILEB + w1024); \
        gl16(Eh + offB1 + (D0), sb + (BUFOFF) + 2 * TILEB + 4096 + w1024); \
        gl16(Em + offB0 + (D0), sb + (BUFOFF) + 3 * TILEB + w1024); \
        gl16(Em + offB1 + (D0), sb + (BUFOFF) + 3 * TILEB + 4096 + w1024); \
    }

    #define COMPUTE(BUFOFF) { \
        f16x8 ah[4], am[4], bh[4], bm[4]; \
        _Pragma("unroll") \
        for (int ai = 0; ai < 4; ++ai) { \
            ah[ai] = *(const f16x8*)(sb + (BUFOFF) + 0 * TILEB + baA + ai * 1024); \
            am[ai] = *(const f16x8*)(sb + (BUFOFF) + 1 * TILEB + baA + ai * 1024); \
        } \
        _Pragma("unroll") \
        for (int bj = 0; bj < 4; ++bj) { \
            bh[bj] = *(const f16x8*)(sb + (BUFOFF) + 2 * TILEB + baB + bj * 1024); \
            bm[bj] = *(const f16x8*)(sb + (BUFOFF) + 3 * TILEB + baB + bj * 1024); \
        } \
        _Pragma("unroll") \
        for (int bj = 0; bj < 4; ++bj) \
            _Pragma("unroll") \
            for (int ai = 0; ai < 4; ++ai) \
                acc1[ai][bj] = __builtin_amdgcn_mfma_f32_16x16x32_f16(ah[ai], bh[bj], acc1[ai][bj], 0, 0, 0); \
        _Pragma("unroll") \
        for (int bj = 0; bj < 4; ++bj) \
            _Pragma("unroll") \
            for (int ai = 0; ai < 4; ++ai) \
                acc2[ai][bj] = __builtin_amdgcn_mfma_f32_16x16x32_f16(ah[ai], bm[bj], acc2[ai][bj], 0, 0, 0); \
        _Pragma("unroll") \
        for (int bj = 0; bj < 4; ++bj) \
            _Pragma("unroll") \
            for (int ai = 0; ai < 4; ++ai) \
                acc2[ai][bj] = __builtin_amdgcn_mfma_f32_16x16x32_f16(am[ai], bh[bj], acc2[ai][bj], 0, 0, 0); \
    }

    // T4 counted-vmcnt pipeline: never drain in-flight prefetch (R6-proven).
    STAGE(0, 0)
    #pragma unroll
    for (int it = 0; it < 8; ++it) {
        int d0 = it * 64;
        STAGE(LBUF, d0 + 32)
        asm volatile("s_waitcnt vmcnt(8)" ::: "memory");
        __builtin_amdgcn_s_barrier();
        __builtin_amdgcn_sched_barrier(0);
        COMPUTE(0)
        __builtin_amdgcn_s_barrier();
        if (it < 7) {
            STAGE(0, d0 + 64)
            asm volatile("s_waitcnt vmcnt(8)" ::: "memory");
        } else {
            asm volatile("s_waitcnt vmcnt(0)" ::: "memory");
        }
        __builtin_amdgcn_s_barrier();
        __builtin_amdgcn_sched_barrier(0);
        COMPUTE(LBUF)
        __builtin_amdgcn_s_barrier();
    }
    #undef STAGE
    #undef COMPUTE

    // ---- epilogue: dot = acc1 + 2^-10 * acc2 ; dist = 2*dot - ||e||^2 ; argmax ----
    const float S = 0.0009765625f;   // 2^-10
    float n2v[4];
    #pragma unroll
    for (int bj = 0; bj < 4; ++bj)
        n2v[bj] = norm2[cBase + wc * 64 + bj * 16 + ln];

    #pragma unroll
    for (int ai = 0; ai < 4; ++ai) {
        #pragma unroll
        for (int r = 0; r < 4; ++r) {
            float bval = -3.4e38f;
            int bidx = 0;
            #pragma unroll
            for (int bj = 0; bj < 4; ++bj) {
                float v = 2.f * (acc1[ai][bj][r] + S * acc2[ai][bj][r]) - n2v[bj];
                if (v > bval) { bval = v; bidx = cBase + wc * 64 + bj * 16 + ln; }
            }
            #pragma unroll
            for (int off = 1; off < 16; off <<= 1) {
                float ov = __shfl_xor(bval, off);
                int   oi = __shfl_xor(bidx, off);
                if (ov > bval || (ov == bval && oi < bidx)) { bval = ov; bidx = oi; }
            }
            if (ln == 0) {
                unsigned long long key =
                    ((unsigned long long)enc_f(bval) << 32) | (unsigned int)(~(unsigned int)bidx);
                atomicMax(&best[rBase + wr * 64 + ai * 16 + kq * 4 + r], key);
            }
        }
    }
}

// ---- phase A: gather quantize + slot allocation (1 tiny atomic/row) ----
__global__ void quant_slot_k(const float* __restrict__ x, const float* __restrict__ embed,
                             const unsigned long long* __restrict__ best,
                             unsigned int* __restrict__ cnt, unsigned int* __restrict__ rowlist,
                             float* __restrict__ out) {
    int row = blockIdx.x, lane = threadIdx.x;
    int idx = (int)(~(unsigned int)best[row]);
    const float4* e = (const float4*)(embed + (size_t)idx * DIM);
    float4* q = (float4*)(out + OUT_QUANT + (size_t)row * DIM);
    q[lane] = e[lane];
    q[lane + 64] = e[lane + 64];
    int pos = 0;
    if (lane == 0) {
        out[OUT_IND + row] = (float)idx;
        pos = (int)atomicAdd(&cnt[idx], 1u);
        if (pos < CAP) rowlist[idx * CAP + pos] = (unsigned)row;
    }
    pos = __shfl(pos, 0);
    if (pos >= CAP) {   // overflow fallback: legacy per-element atomic scatter
        const float4* xr = (const float4*)(x + (size_t)row * DIM);
        float* avg = out + OUT_AVG + (size_t)idx * DIM;
        #pragma unroll
        for (int j = lane; j < DIM / 4; j += 64) {
            float4 xv = xr[j];
            atomicAdd(&avg[j * 4 + 0], 0.2f * xv.x);
            atomicAdd(&avg[j * 4 + 1], 0.2f * xv.y);
            atomicAdd(&avg[j * 4 + 2], 0.2f * xv.z);
            atomicAdd(&avg[j * 4 + 3], 0.2f * xv.w);
        }
    }
}

// ---- phase B: per-code row-list reduce, atomic-free (one block per code) ----
__global__ void csum_k(const float* __restrict__ x, const unsigned int* __restrict__ cnt,
                       const unsigned int* __restrict__ rowlist, float* __restrict__ out) {
    int code = blockIdx.x, lane = threadIdx.x;
    int n = (int)cnt[code];
    if (n == 0) return;
    int m = n < CAP ? n : CAP;
    float4 a0 = {0.f, 0.f, 0.f, 0.f}, a1 = {0.f, 0.f, 0.f, 0.f};
    for (int t = 0; t < m; ++t) {
        int row = (int)rowlist[code * CAP + t];
        const float4* xr = (const float4*)(x + (size_t)row * DIM);
        float4 v0 = xr[lane], v1 = xr[lane + 64];
        a0.x += v0.x; a0.y += v0.y; a0.z += v0.z; a0.w += v0.w;
        a1.x += v1.x; a1.y += v1.y; a1.z += v1.z; a1.w += v1.w;
    }
    float4* av = (float4*)(out + OUT_AVG + (size_t)code * DIM);
    float4 c0 = av[lane], c1 = av[lane + 64];
    c0.x += 0.2f * a0.x; c0.y += 0.2f * a0.y; c0.z += 0.2f * a0.z; c0.w += 0.2f * a0.w;
    c1.x += 0.2f * a1.x; c1.y += 0.2f * a1.y; c1.z += 0.2f * a1.z; c1.w += 0.2f * a1.w;
    av[lane] = c0;
    av[lane + 64] = c1;
    if (lane == 0) out[OUT_CSN + code] += 0.2f * (float)n;
}

// ---- fused: S = sum(csn) then inv_cs[k] ----
__global__ void sumInv_k(const float* __restrict__ out, float* __restrict__ Sout,
                         float* __restrict__ inv_cs) {
    __shared__ float red[4];
    float s = 0.f;
    for (int i = threadIdx.x; i < KCODES; i += 256) s += out[OUT_CSN + i];
    #pragma unroll
    for (int off = 32; off; off >>= 1) s += __shfl_down(s, off);
    if ((threadIdx.x & 63) == 0) red[threadIdx.x >> 6] = s;
    __syncthreads();
    float Sv = red[0] + red[1] + red[2] + red[3];
    if (threadIdx.x == 0) Sout[0] = Sv;
    for (int k = threadIdx.x; k < KCODES; k += 256)
        inv_cs[k] = (Sv + (float)KCODES * EPSF) / ((out[OUT_CSN + k] + EPSF) * Sv);
}

__global__ void normout_k(float* __restrict__ out, const float* __restrict__ inv_cs) {
    int i = blockIdx.x * 256 + threadIdx.x;
    const float4* avg = (const float4*)(out + OUT_AVG);
    float4* nrm = (float4*)(out + OUT_NORM);
    float inv = inv_cs[i >> 7];
    float4 v = avg[i];
    v.x *= inv; v.y *= inv; v.z *= inv; v.w *= inv;
    nrm[i] = v;
}

extern "C" void kernel_launch(void* const* d_in, const int* in_sizes, int n_in,
                              void* d_out, int out_size, void* d_ws, size_t ws_size,
                              hipStream_t stream) {
    const float* x     = (const float*)d_in[0];
    const float* embed = (const float*)d_in[1];
    const float* cs    = (const float*)d_in[2];
    const float* eavg  = (const float*)d_in[3];
    float* out = (float*)d_out;
    char*  w   = (char*)d_ws;

    unsigned long long* best = (unsigned long long*)w;
    float* norm2  = (float*)(w + 262144);
    float* Ssum   = (float*)(w + 294912);
    float* inv_cs = Ssum + 1;
    _Float16* Eh = (_Float16*)(w + (1u << 20));
    _Float16* Em = Eh + (size_t)KCODES * DIM;
    unsigned int* cnt     = (unsigned int*)(w + (20u << 20));
    unsigned int* rowlist = cnt + KCODES;

    // X planes exactly fill the quant region (64 MiB), rewritten later by quant_slot_k
    _Float16* Xh = (_Float16*)out;
    _Float16* Xm = Xh + (size_t)N_ROWS * DIM;

    cvt_x_k<<<(N_ROWS * DIM / 8) / 256, 256, 0, stream>>>(x, Xh, Xm, best, cnt, cs, eavg, out);
    cvt_e_k<<<(KCODES * DIM / 8) / 256, 256, 0, stream>>>(embed, Eh, Em, norm2);
    dist_k<<<(N_ROWS / BM) * (KCODES / BN), 256, 0, stream>>>(Xh, Xm, Eh, Em, norm2, best);
    quant_slot_k<<<N_ROWS, 64, 0, stream>>>(x, embed, best, cnt, rowlist, out);
    csum_k<<<KCODES, 64, 0, stream>>>(x, cnt, rowlist, out);
    sumInv_k<<<1, 256, 0, stream>>>(out, Ssum, inv_cs);
    normout_k<<<(KCODES * DIM / 4) / 256, 256, 0, stream>>>(out, inv_cs);
}